// Round 4
// baseline (243.188 us; speedup 1.0000x reference)
//
#include <hip/hip_runtime.h>

// LeakyIntegrator: T=4096 scan over B=8192 columns, fp32. x is EXACTLY {0,1}.
// Algebraic reduction: with m_t = d*(m_{t-1}+x_t)   (= n10+n11, decayed ones),
//   na1_t = m_{t-1}                       (EXACT identity, same fp op sequence)
//   na0_t = S_t - m_{t-1},  S_t = d*(S_{t-1}+1) = d(1-d^t)/(1-d)   (data-independent)
//   n10_t = m_t - n11_t
// => only TWO data-dependent states (m, n11) + bit-packed x (u32 per 32-row chunk).
// Round 4 geometry: NCHUNK=128, CLEN=32, VEC=4 -> BOTH 1 KiB/wave-instr dwordx4
// streaming (round-1's win) AND 1024 blocks = 4 blocks/CU (round-3's win).
// __launch_bounds__(256,4) caps VGPR at 128 to guarantee co-residency.
// ws layout (12 MiB):
//   [0, 4 MiB)  : m   locals [NCHUNK][B_DIM] float
//   [4, 8 MiB)  : n11 locals [NCHUNK][B_DIM] float
//   [8, 12 MiB) : packed x bits [NCHUNK][B_DIM] u32

constexpr int T_DIM  = 4096;
constexpr int B_DIM  = 8192;
constexpr int NCHUNK = 128;
constexpr int CLEN   = T_DIM / NCHUNK;   // 32
constexpr int VEC    = 4;                // columns per thread (float4)
constexpr int UNROLL = 4;                // rows per load batch (2-batch pipeline)
constexpr int BLOCK  = 256;

typedef float v4f __attribute__((ext_vector_type(4)));
typedef unsigned int u32;
typedef u32 v4u __attribute__((ext_vector_type(4)));

__global__ __launch_bounds__(BLOCK, 4) void partial_kernel(
    const float* __restrict__ x, const float* __restrict__ dptr,
    float* __restrict__ ws)
{
    const float d  = *dptr;
    const int   c  = blockIdx.y;
    const int   b0 = (blockIdx.x * BLOCK + (int)threadIdx.x) * VEC;
    const long  t0 = (long)c * CLEN;

    float prev[VEC];
    if (c == 0) {
        #pragma unroll
        for (int j = 0; j < VEC; ++j) prev[j] = 0.0f;
    } else {
        const v4f pv = *reinterpret_cast<const v4f*>(x + (t0 - 1) * B_DIM + b0);
        #pragma unroll
        for (int j = 0; j < VEC; ++j) prev[j] = pv[j];
    }

    float m[VEC]   = {0.f, 0.f, 0.f, 0.f};
    float n11[VEC] = {0.f, 0.f, 0.f, 0.f};
    u32   mask[VEC] = {0u, 0u, 0u, 0u};

    const float* p = x + t0 * B_DIM + b0;

    // two-batch software pipeline: next batch's loads in flight while current
    // batch is consumed. Static indexing only (named A/Bv), full unroll.
    v4f A[UNROLL], Bv[UNROLL];
    #pragma unroll
    for (int u = 0; u < UNROLL; ++u)
        A[u] = *reinterpret_cast<const v4f*>(p + (size_t)u * B_DIM);

    auto compute = [&](const v4f* buf, int kbase) {
        #pragma unroll
        for (int u = 0; u < UNROLL; ++u) {
            const int k = kbase + u;
            #pragma unroll
            for (int j = 0; j < VEC; ++j) {
                const float xt = buf[u][j];
                mask[j] |= (u32)xt << k;             // xt is exactly 0.0 or 1.0
                m[j]   = d * (m[j] + xt);
                n11[j] = d * (n11[j] + xt * prev[j]);
                prev[j] = xt;
            }
        }
    };

    #pragma unroll
    for (int kk = 0; kk < CLEN; kk += 2 * UNROLL) {
        #pragma unroll
        for (int u = 0; u < UNROLL; ++u)
            Bv[u] = *reinterpret_cast<const v4f*>(p + (size_t)(kk + UNROLL + u) * B_DIM);
        compute(A, kk);
        if (kk + 2 * UNROLL < CLEN) {               // compile-time after unroll
            #pragma unroll
            for (int u = 0; u < UNROLL; ++u)
                A[u] = *reinterpret_cast<const v4f*>(p + (size_t)(kk + 2 * UNROLL + u) * B_DIM);
        }
        compute(Bv, kk + UNROLL);
    }

    // locals + bits are consumed by the NEXT kernels: nontemporal keeps L2 clean.
    float* wm = ws + (size_t)c * B_DIM + b0;
    v4f mv, nv;
    #pragma unroll
    for (int j = 0; j < VEC; ++j) { mv[j] = m[j]; nv[j] = n11[j]; }
    __builtin_nontemporal_store(mv, reinterpret_cast<v4f*>(wm));
    __builtin_nontemporal_store(nv, reinterpret_cast<v4f*>(wm + (size_t)NCHUNK * B_DIM));

    u32* bits = reinterpret_cast<u32*>(ws + (size_t)2 * NCHUNK * B_DIM);
    v4u bm;
    #pragma unroll
    for (int j = 0; j < VEC; ++j) bm[j] = mask[j];
    __builtin_nontemporal_store(bm, reinterpret_cast<v4u*>(&bits[(size_t)c * B_DIM + b0]));
}

// One thread per (state, column): 2*8192 = 16384 threads, 64-thread blocks so
// all 256 CUs participate. 4 groups of 32 locals with group-ahead prefetch.
__global__ __launch_bounds__(64) void scan_kernel(
    const float* __restrict__ dptr, float* __restrict__ ws)
{
    float dL = *dptr;                 // d^CLEN, CLEN = 32 = 2^5
    #pragma unroll
    for (int i = 0; i < 5; ++i) dL = dL * dL;

    const int tid = blockIdx.x * 64 + (int)threadIdx.x;   // [0, 2*B)
    float* p = ws + (size_t)(tid >> 13) * NCHUNK * B_DIM + (tid & (B_DIM - 1));

    constexpr int G  = 32;
    constexpr int NG = NCHUNK / G;    // 4
    float cur[G], nxt[G];
    #pragma unroll
    for (int i = 0; i < G; ++i) cur[i] = p[(size_t)i * B_DIM];

    float s = 0.f;
    #pragma unroll
    for (int g = 0; g < NG; ++g) {                  // fully unrolled: static idx
        if (g + 1 < NG) {
            #pragma unroll
            for (int i = 0; i < G; ++i)
                nxt[i] = p[(size_t)((g + 1) * G + i) * B_DIM];
        }
        #pragma unroll
        for (int i = 0; i < G; ++i) {
            p[(size_t)(g * G + i) * B_DIM] = s;     // incoming state for chunk
            s = dL * s + cur[i];
        }
        if (g + 1 < NG) {
            #pragma unroll
            for (int i = 0; i < G; ++i) cur[i] = nxt[i];
        }
    }
}

__global__ __launch_bounds__(BLOCK, 4) void final_kernel(
    const float* __restrict__ dptr, const float* __restrict__ ws,
    float* __restrict__ out)
{
    const float d = *dptr;
    float dL = d;
    #pragma unroll
    for (int i = 0; i < 5; ++i) dL = dL * dL;                  // d^32

    const int c  = blockIdx.y;
    const int b0 = (blockIdx.x * BLOCK + (int)threadIdx.x) * VEC;

    const float* w = ws + (size_t)c * B_DIM + b0;
    const v4f mi = *reinterpret_cast<const v4f*>(w);
    const v4f ni = *reinterpret_cast<const v4f*>(w + (size_t)NCHUNK * B_DIM);
    float m[VEC], n11[VEC];
    #pragma unroll
    for (int j = 0; j < VEC; ++j) { m[j] = mi[j]; n11[j] = ni[j]; }

    // incoming na_sum = d*(1 - d^(32c)) / (1-d); 1-d is EXACT for d in [0.5,1)
    float dLc = 1.f, sq = dL;
    int cc = c;
    #pragma unroll
    for (int i = 0; i < 7; ++i) { if (cc & 1) dLc *= sq; sq *= sq; cc >>= 1; }
    float na = d * (1.f - dLc) / (1.f - d);

    const u32* bits = reinterpret_cast<const u32*>(ws + (size_t)2 * NCHUNK * B_DIM);
    const v4u bm = *reinterpret_cast<const v4u*>(&bits[(size_t)c * B_DIM + b0]);
    u32 mask[VEC];
    #pragma unroll
    for (int j = 0; j < VEC; ++j) mask[j] = bm[j];

    bool pb[VEC];
    if (c == 0) {
        #pragma unroll
        for (int j = 0; j < VEC; ++j) pb[j] = false;
    } else {
        const v4u pm = *reinterpret_cast<const v4u*>(&bits[(size_t)(c - 1) * B_DIM + b0]);
        #pragma unroll
        for (int j = 0; j < VEC; ++j) pb[j] = (pm[j] >> 31) & 1u;
    }

    float* q = out + (size_t)c * CLEN * B_DIM + b0;
    #pragma unroll
    for (int kk = 0; kk < CLEN; kk += UNROLL) {
        #pragma unroll
        for (int u = 0; u < UNROLL; ++u) {
            const int k = kk + u;
            na = d * (na + 1.f);                     // uniform, 1 op per row
            float pr[VEC];
            #pragma unroll
            for (int j = 0; j < VEC; ++j) {
                const bool  xb = (mask[j] >> k) & 1u;
                const float mo = m[j];               // = na1_t (exact identity)
                m[j]   = d * (mo + (xb ? 1.f : 0.f));
                n11[j] = d * (n11[j] + ((xb && pb[j]) ? 1.f : 0.f));
                const float num = xb ? (n11[j] + 1.f) : (m[j] - n11[j] + 1.f);
                const float den = xb ? (mo + 2.f)     : (na - mo + 2.f);
                pr[j] = num * __builtin_amdgcn_rcpf(den);   // ONE rcp per element
                pb[j] = xb;
            }
            v4f ov;
            #pragma unroll
            for (int j = 0; j < VEC; ++j) ov[j] = pr[j];
            __builtin_nontemporal_store(ov, reinterpret_cast<v4f*>(q + (size_t)u * B_DIM));
        }
        q += (size_t)UNROLL * B_DIM;
    }
}

extern "C" void kernel_launch(void* const* d_in, const int* in_sizes, int n_in,
                              void* d_out, int out_size, void* d_ws, size_t ws_size,
                              hipStream_t stream) {
    const float* x  = (const float*)d_in[0];
    const float* dr = (const float*)d_in[1];
    float* ws  = (float*)d_ws;    // needs 12 MiB
    float* out = (float*)d_out;

    dim3 blk(BLOCK);
    dim3 grid1(B_DIM / VEC / BLOCK, NCHUNK);   // (8, 128) = 1024 blocks
    partial_kernel<<<grid1, blk, 0, stream>>>(x, dr, ws);
    scan_kernel<<<(2 * B_DIM) / 64, dim3(64), 0, stream>>>(dr, ws);
    final_kernel<<<grid1, blk, 0, stream>>>(dr, ws, out);
}